// Round 1
// baseline (45.119 us; speedup 1.0000x reference)
//
#include <hip/hip_runtime.h>

// out[i] = A_source[i] + b2 + sum_j W2[j] * tanh(W1[j][0]*c_target[i] + W1[j][1]*wavelength[i] + b1[j])
// (W1[j][2] multiplies a zero; c_source is unused by the reference.)
//
// Memory-bound elementwise op: 12 B in + 4 B out per element. float4-vectorized,
// grid-stride, params hoisted to registers, tanh via one v_exp_f32 per hidden unit.

#define HGEO 8

__global__ __launch_bounds__(256) void geodesic_kernel(
    const float4* __restrict__ c_target,
    const float4* __restrict__ wavelength,
    const float4* __restrict__ A_source,
    const float* __restrict__ W1,   // [8][3] row-major
    const float* __restrict__ b1,   // [8]
    const float* __restrict__ W2,   // [8]
    const float* __restrict__ b2,   // [1]
    float4* __restrict__ out,
    int n4)
{
    // Hoist params into registers (uniform loads, L1/L2 broadcast).
    float wa[HGEO], wb[HGEO], bb[HGEO], wo[HGEO];
#pragma unroll
    for (int j = 0; j < HGEO; ++j) {
        wa[j] = W1[j * 3 + 0];
        wb[j] = W1[j * 3 + 1];
        bb[j] = b1[j];
        wo[j] = W2[j];
    }
    const float bias2 = b2[0];

    const int stride = gridDim.x * blockDim.x;
    for (int i = blockIdx.x * blockDim.x + threadIdx.x; i < n4; i += stride) {
        float4 c = c_target[i];
        float4 w = wavelength[i];
        float4 a = A_source[i];

        const float cv[4] = {c.x, c.y, c.z, c.w};
        const float wv[4] = {w.x, w.y, w.z, w.w};
        const float av[4] = {a.x, a.y, a.z, a.w};
        float ov[4];

#pragma unroll
        for (int k = 0; k < 4; ++k) {
            float s = av[k] + bias2;
#pragma unroll
            for (int j = 0; j < HGEO; ++j) {
                float z = fmaf(wa[j], cv[k], fmaf(wb[j], wv[k], bb[j]));
                // tanh(z) = 1 - 2/(exp(2z)+1); exp2 maps to a single v_exp_f32.
                float e = exp2f(z * 2.885390081777927f);  // 2/ln(2)
                float h = 1.0f - 2.0f / (e + 1.0f);
                s = fmaf(wo[j], h, s);
            }
            ov[k] = s;
        }
        out[i] = make_float4(ov[0], ov[1], ov[2], ov[3]);
    }
}

extern "C" void kernel_launch(void* const* d_in, const int* in_sizes, int n_in,
                              void* d_out, int out_size, void* d_ws, size_t ws_size,
                              hipStream_t stream) {
    // Input order per setup_inputs(): c_source, c_target, wavelength, A_source, W1, b1, W2, b2
    const float4* c_target   = (const float4*)d_in[1];
    const float4* wavelength = (const float4*)d_in[2];
    const float4* A_source   = (const float4*)d_in[3];
    const float*  W1 = (const float*)d_in[4];
    const float*  b1 = (const float*)d_in[5];
    const float*  W2 = (const float*)d_in[6];
    const float*  b2 = (const float*)d_in[7];
    float4* out = (float4*)d_out;

    const int n4 = out_size / 4;  // out_size = 8388608, divisible by 4
    const int threads = 256;
    const int blocks = 2048;      // grid-stride covers the rest
    geodesic_kernel<<<blocks, threads, 0, stream>>>(
        c_target, wavelength, A_source, W1, b1, W2, b2, out, n4);
}

// Round 2
// 27.963 us; speedup vs baseline: 1.6135x; 1.6135x over previous
//
#include <hip/hip_runtime.h>

// out[i] = A_source[i] + b2 + sum_j W2[j] * tanh(W1[j][0]*c_target[i] + W1[j][1]*wavelength[i] + b1[j])
// (W1[j][2] multiplies a zero; c_source is unused by the reference.)
//
// tanh(z) = 1 - 2/(exp2(z*2/ln2)+1).  Folds:
//   wa' = W1[j][0]*2/ln2, wb' = W1[j][1]*2/ln2, bb' = b1[j]*2/ln2
//   s   = (A + b2 + sum_j W2[j]) + sum_j (-2*W2[j]) * rcp(exp2(z')+1)
// rcp via v_rcp_f32 (__builtin_amdgcn_rcpf): avoids the IEEE div sequence
// (~10 VALU ops each) that made round-1 VALU-bound (VALUBusy 75%, HBM 20%).

#define HGEO 8

__global__ __launch_bounds__(256) void geodesic_kernel(
    const float4* __restrict__ c_target,
    const float4* __restrict__ wavelength,
    const float4* __restrict__ A_source,
    const float* __restrict__ W1,   // [8][3] row-major
    const float* __restrict__ b1,   // [8]
    const float* __restrict__ W2,   // [8]
    const float* __restrict__ b2,   // [1]
    float4* __restrict__ out,
    int n4)
{
    const float K = 2.885390081777927f;  // 2/ln(2)

    float wa[HGEO], wb[HGEO], bb[HGEO], wo2[HGEO];
    float s0 = b2[0];
#pragma unroll
    for (int j = 0; j < HGEO; ++j) {
        wa[j]  = W1[j * 3 + 0] * K;
        wb[j]  = W1[j * 3 + 1] * K;
        bb[j]  = b1[j] * K;
        float wo = W2[j];
        wo2[j] = -2.0f * wo;
        s0 += wo;
    }

    const int i = blockIdx.x * blockDim.x + threadIdx.x;
    if (i >= n4) return;

    float4 c = c_target[i];
    float4 w = wavelength[i];
    float4 a = A_source[i];

    const float cv[4] = {c.x, c.y, c.z, c.w};
    const float wv[4] = {w.x, w.y, w.z, w.w};
    const float av[4] = {a.x, a.y, a.z, a.w};
    float ov[4];

#pragma unroll
    for (int k = 0; k < 4; ++k) {
        float s = av[k] + s0;
#pragma unroll
        for (int j = 0; j < HGEO; ++j) {
            float z = fmaf(wa[j], cv[k], fmaf(wb[j], wv[k], bb[j]));
            float e = exp2f(z);                       // one v_exp_f32
            float r = __builtin_amdgcn_rcpf(e + 1.0f); // one v_rcp_f32
            s = fmaf(wo2[j], r, s);
        }
        ov[k] = s;
    }
    out[i] = make_float4(ov[0], ov[1], ov[2], ov[3]);
}

extern "C" void kernel_launch(void* const* d_in, const int* in_sizes, int n_in,
                              void* d_out, int out_size, void* d_ws, size_t ws_size,
                              hipStream_t stream) {
    // Input order per setup_inputs(): c_source, c_target, wavelength, A_source, W1, b1, W2, b2
    const float4* c_target   = (const float4*)d_in[1];
    const float4* wavelength = (const float4*)d_in[2];
    const float4* A_source   = (const float4*)d_in[3];
    const float*  W1 = (const float*)d_in[4];
    const float*  b1 = (const float*)d_in[5];
    const float*  W2 = (const float*)d_in[6];
    const float*  b2 = (const float*)d_in[7];
    float4* out = (float4*)d_out;

    const int n4 = out_size / 4;        // 2097152
    const int threads = 256;
    const int blocks = (n4 + threads - 1) / threads;  // 8192 — one float4 per thread
    geodesic_kernel<<<blocks, threads, 0, stream>>>(
        c_target, wavelength, A_source, W1, b1, W2, b2, out, n4);
}